// Round 7
// baseline (115.431 us; speedup 1.0000x reference)
//
#include <hip/hip_runtime.h>
#include <math.h>

#define BB 8
#define TT 4096
#define EE 64
#define DD 8
// (1/sqrt(8)) * log2(e): folded into q so p = exp2(score) directly
#define QSCALE 0.51012604f
// fixed softmax shift, implemented as MFMA C-init; cancels in normalization
#define CSHIFT -12.0f

typedef _Float16 half8  __attribute__((ext_vector_type(8)));
typedef _Float16 half4v __attribute__((ext_vector_type(4)));
typedef float    floatx4 __attribute__((ext_vector_type(4)));

// ---------------------------------------------------------------------------
// Kernel 1: projections (unchanged). Block owns 32 rows t = g*512 + tbase + j
// so the ks "reshape" scatter is one contiguous 512-B region. vT rows:
// 0-7 = v^T, row 8 = ones (softmax denominator rides in O^T[8]).
// ---------------------------------------------------------------------------
__global__ __launch_bounds__(256) void proj_kernel(
    const float* __restrict__ x,
    const float* __restrict__ Wq, const float* __restrict__ bq,
    const float* __restrict__ Wk, const float* __restrict__ bk,
    const float* __restrict__ Wv, const float* __restrict__ bv,
    _Float16* __restrict__ qh, _Float16* __restrict__ ks, _Float16* __restrict__ vT)
{
    __shared__ float    xs[32][EE + 1];
    __shared__ _Float16 qsm[256];   // [g][j][d] == tid order
    __shared__ _Float16 ksm[256];   // [j][d][g]
    __shared__ _Float16 vsm[256];   // [d][r]

    const int tid   = threadIdx.x;
    const int blk   = blockIdx.x;
    const int b     = blk >> 7;
    const int tbase = (blk & 127) << 2;

#pragma unroll
    for (int m2 = 0; m2 < 2; ++m2) {
        int r = (tid >> 4) + (m2 << 4);
        int c = (tid & 15) << 2;
        int t = ((r >> 2) << 9) + tbase + (r & 3);
        float4 a = *(const float4*)(x + (size_t)(b * TT + t) * EE + c);
        xs[r][c+0] = a.x; xs[r][c+1] = a.y; xs[r][c+2] = a.z; xs[r][c+3] = a.w;
    }
    __syncthreads();

    const int r = tid >> 3;
    const int d = tid & 7;
    float accq = bq[d], acck = bk[d], accv = bv[d];
#pragma unroll
    for (int e = 0; e < EE; ++e) {
        float xv = xs[r][e];
        accq = fmaf(xv, Wq[e*DD + d], accq);
        acck = fmaf(xv, Wk[e*DD + d], acck);
        accv = fmaf(xv, Wv[e*DD + d], accv);
    }
    qsm[tid] = (_Float16)(accq * QSCALE);
    ksm[((r & 3) << 6) + (d << 3) + (r >> 2)] = (_Float16)acck;
    vsm[(d << 5) + r] = (_Float16)accv;
    __syncthreads();

    if (tid < 32) {
        half8 qv = *(half8*)(qsm + tid * 8);
        *(half8*)(qh + (size_t)b*(TT*DD) + (size_t)(tid >> 2)*(512*DD)
                     + (size_t)tbase*DD + ((tid & 3) << 3)) = qv;
        half8 kv = *(half8*)(ksm + tid * 8);
        *(half8*)(ks + (size_t)b*(TT*DD) + (size_t)tbase*64 + tid * 8) = kv;
    } else if (tid >= 64 && tid < 128) {
        int idx = tid - 64, d2 = idx >> 3, g2 = idx & 7;
        half4v vv = *(half4v*)(vsm + (d2 << 5) + (g2 << 2));
        *(half4v*)(vT + (size_t)b*(16*TT) + (size_t)d2*TT + (g2 << 9) + tbase) = vv;
    } else if (tid >= 128 && tid < 136) {
        int g2 = tid - 128;
        half4v ones = {(_Float16)1.0f, (_Float16)1.0f, (_Float16)1.0f, (_Float16)1.0f};
        *(half4v*)(vT + (size_t)b*(16*TT) + (size_t)8*TT + (g2 << 9) + tbase) = ones;
    }
}

// ---------------------------------------------------------------------------
// Kernel 2: MFMA flash attention, fixed-shift softmax. Round-7:
//  SHUFFLE-FREE PV. The k-slot->t2 assignment in the PV MFMA is arbitrary
//  (PV sums over all t2 in the item), so pick t2map(q,j) = s*16 + q*4 + j%4
//  (s = 2*pv + j/4). Then the PV B-operand is the lane's OWN S registers
//  {lo[s0],hi[s0],lo[s1],hi[s1]} - zero cross-lane moves - and V is loaded
//  at matching addresses: 4 x b64 at vq + t2base + s*16 (vq has a +q*4
//  per-quad offset). Replaces 16 ds_bpermute + 8 cndmask per item.
// ---------------------------------------------------------------------------
__global__ __launch_bounds__(512, 4) void attn_kernel(
    const _Float16* __restrict__ qh, const _Float16* __restrict__ ks,
    const _Float16* __restrict__ vT, float* __restrict__ out)
{
    __shared__ floatx4 obuf[2][8][64];

    const int lane = threadIdx.x & 63;
    const int wave = threadIdx.x >> 6;
    const int g = lane >> 4;
    const int n = lane & 15;

    const int blk = blockIdx.x;
    const int bb  = blk >> 7;
    const int p   = blk & 127;
    const int ntA = (p >> 2) + 1;
    const int ntB = ((255 - p) >> 2) + 1;
    const int r0A = p << 4;
    const int r0B = (255 - p) << 4;

    const _Float16* ksb = ks + (size_t)bb * (TT*DD);
    const _Float16* vTb = vT + (size_t)bb * (16*TT);
    // V A-operand base: lane (quad g, n=d') reads t2 = t2base + s*16 + g*4 + 0..3
    const _Float16* vq = vTb + (size_t)n * TT + (g << 2);

    half8 qfA, qfB;
    {
        half8 z;
#pragma unroll
        for (int j = 0; j < 8; ++j) z[j] = (_Float16)0.0f;
        qfA = z; qfB = z;
        if (g == 0) {
            qfA = *(const half8*)(qh + ((size_t)bb*TT + r0A + n) * DD);
            qfB = *(const half8*)(qh + ((size_t)bb*TT + r0B + n) * DD);
        }
    }

    floatx4 oA = {0.f, 0.f, 0.f, 0.f};
    floatx4 oB = {0.f, 0.f, 0.f, 0.f};
    const floatx4 C12 = {CSHIFT, CSHIFT, CSHIFT, CSHIFT};

#define ATTN_LOOP(NT, R0, QF, OACC)                                             \
    for (int i = wave; i < (NT); i += 8) {                                      \
        const int t2base = i << 6;                                              \
        const _Float16* kp = ksb + (size_t)(t2base + n) * DD;                   \
        half8 ck0 = *(const half8*)(kp);                                        \
        half8 ck1 = *(const half8*)(kp + 16 * DD);                              \
        half8 ck2 = *(const half8*)(kp + 32 * DD);                              \
        half8 ck3 = *(const half8*)(kp + 48 * DD);                              \
        int2 w0 = *(const int2*)(vq + t2base);                                  \
        int2 w1 = *(const int2*)(vq + t2base + 16);                             \
        int2 w2 = *(const int2*)(vq + t2base + 32);                             \
        int2 w3 = *(const int2*)(vq + t2base + 48);                             \
        floatx4 S[4];                                                           \
        S[0] = __builtin_amdgcn_mfma_f32_16x16x32_f16(ck0, QF, C12, 0, 0, 0);   \
        S[1] = __builtin_amdgcn_mfma_f32_16x16x32_f16(ck1, QF, C12, 0, 0, 0);   \
        S[2] = __builtin_amdgcn_mfma_f32_16x16x32_f16(ck2, QF, C12, 0, 0, 0);   \
        S[3] = __builtin_amdgcn_mfma_f32_16x16x32_f16(ck3, QF, C12, 0, 0, 0);   \
        if (t2base + 63 > (R0)) {                                               \
            const int lim = (R0) + n - t2base - (g << 2);                       \
            _Pragma("unroll")                                                   \
            for (int s = 0; s < 4; ++s)                                         \
                _Pragma("unroll")                                               \
                for (int rr = 0; rr < 4; ++rr)                                  \
                    if ((s << 4) + rr > lim) S[s][rr] = -INFINITY;              \
        }                                                                       \
        int lo[4], hi[4];                                                       \
        _Pragma("unroll")                                                       \
        for (int s = 0; s < 4; ++s) {                                           \
            float p0 = __builtin_amdgcn_exp2f(S[s][0]);                         \
            float p1 = __builtin_amdgcn_exp2f(S[s][1]);                         \
            float p2 = __builtin_amdgcn_exp2f(S[s][2]);                         \
            float p3 = __builtin_amdgcn_exp2f(S[s][3]);                         \
            lo[s] = __builtin_bit_cast(int, __builtin_amdgcn_cvt_pkrtz(p0, p1));\
            hi[s] = __builtin_bit_cast(int, __builtin_amdgcn_cvt_pkrtz(p2, p3));\
        }                                                                       \
        /* PV0: subtiles 0,1 — own-register B operand, V at matching t2 */      \
        {                                                                       \
            int4 bi; bi.x = lo[0]; bi.y = hi[0]; bi.z = lo[1]; bi.w = hi[1];    \
            int4 ai; ai.x = w0.x; ai.y = w0.y; ai.z = w1.x; ai.w = w1.y;        \
            half8 pb = __builtin_bit_cast(half8, bi);                           \
            half8 va = __builtin_bit_cast(half8, ai);                           \
            OACC = __builtin_amdgcn_mfma_f32_16x16x32_f16(va, pb, OACC, 0, 0, 0);\
        }                                                                       \
        /* PV1: subtiles 2,3 */                                                 \
        {                                                                       \
            int4 bi; bi.x = lo[2]; bi.y = hi[2]; bi.z = lo[3]; bi.w = hi[3];    \
            int4 ai; ai.x = w2.x; ai.y = w2.y; ai.z = w3.x; ai.w = w3.y;        \
            half8 pb = __builtin_bit_cast(half8, bi);                           \
            half8 va = __builtin_bit_cast(half8, ai);                           \
            OACC = __builtin_amdgcn_mfma_f32_16x16x32_f16(va, pb, OACC, 0, 0, 0);\
        }                                                                       \
    }

    ATTN_LOOP(ntA, r0A, qfA, oA)
    ATTN_LOOP(ntB, r0B, qfB, oB)
#undef ATTN_LOOP

    obuf[0][wave][lane] = oA;
    obuf[1][wave][lane] = oB;
    __syncthreads();

    // ---- merge: plain sum of 8 partials (fixed shift -> no rebasing) ----
    if (wave < 2) {
        floatx4 osum = {0.f, 0.f, 0.f, 0.f};
#pragma unroll
        for (int w = 0; w < 8; ++w) osum += obuf[wave][w][lane];
        const float l    = __shfl(osum[0], 32 + n, 64);  // O^T[8][t1]
        const float linv = 1.0f / l;
        const int   r0   = wave ? r0B : r0A;
        if (g < 2) {
            float4 res;
            res.x = osum[0] * linv; res.y = osum[1] * linv;
            res.z = osum[2] * linv; res.w = osum[3] * linv;
            *(float4*)(out + (((size_t)bb * TT + r0 + n) * DD) + (g << 2)) = res;
        }
    }
}

extern "C" void kernel_launch(void* const* d_in, const int* in_sizes, int n_in,
                              void* d_out, int out_size, void* d_ws, size_t ws_size,
                              hipStream_t stream) {
    const float* x  = (const float*)d_in[0];
    const float* Wq = (const float*)d_in[1];
    const float* bq = (const float*)d_in[2];
    const float* Wk = (const float*)d_in[3];
    const float* bk = (const float*)d_in[4];
    const float* Wv = (const float*)d_in[5];
    const float* bv = (const float*)d_in[6];
    float* out = (float*)d_out;

    _Float16* qhp = (_Float16*)d_ws;                       // B*T*D
    _Float16* ksp = qhp + (size_t)BB * TT * DD;            // B*T*D
    _Float16* vTp = ksp + (size_t)BB * TT * DD;            // B*16*T

    proj_kernel<<<BB * TT / 32, 256, 0, stream>>>(x, Wq, bq, Wk, bk, Wv, bv, qhp, ksp, vTp);
    attn_kernel<<<1024, 512, 0, stream>>>(qhp, ksp, vTp, out);
}

// Round 8
// 90.503 us; speedup vs baseline: 1.2754x; 1.2754x over previous
//
#include <hip/hip_runtime.h>
#include <math.h>

#define BB 8
#define TT 4096
#define EE 64
#define DD 8
// (1/sqrt(8)) * log2(e): folded into q so p = exp2(score) directly
#define QSCALE 0.51012604f
// fixed softmax shift, implemented as MFMA C-init; cancels in normalization
#define CSHIFT -12.0f

typedef _Float16 half8  __attribute__((ext_vector_type(8)));
typedef _Float16 half4v __attribute__((ext_vector_type(4)));
typedef float    floatx4 __attribute__((ext_vector_type(4)));

// vP: per batch, 64 items x [pv:2] x [lane:64] x 8 halfs = 65536 halfs.
// vP[i][pv][g*16+n][j] = V^T[n][i*64 + pv*32 + (j<4 ? g*4+j : 16+g*4+j-4)]
// (n=8 -> 1.0 denominator row; n>8 garbage/ignored)
#define VP_BATCH 65536

// ---------------------------------------------------------------------------
// Kernel 1: projections. Block owns 32 rows t = g2x*512 + tbase + jx. ks
// "reshape" scatter = one contiguous 512-B region. V is written PRE-SWIZZLED
// into the PV MFMA A-operand lane order (vP) so attn V-loads are contiguous.
// ---------------------------------------------------------------------------
__global__ __launch_bounds__(256) void proj_kernel(
    const float* __restrict__ x,
    const float* __restrict__ Wq, const float* __restrict__ bq,
    const float* __restrict__ Wk, const float* __restrict__ bk,
    const float* __restrict__ Wv, const float* __restrict__ bv,
    _Float16* __restrict__ qh, _Float16* __restrict__ ks, _Float16* __restrict__ vP)
{
    __shared__ float    xs[32][EE + 1];
    __shared__ _Float16 qsm[256];   // [g2x][jx][d] == tid order
    __shared__ _Float16 ksm[256];   // [jx][d][g2x]
    __shared__ _Float16 vsm[256];   // [d][r]  (r = g2x*4 + jx)

    const int tid   = threadIdx.x;
    const int blk   = blockIdx.x;
    const int b     = blk >> 7;
    const int tbase = (blk & 127) << 2;

#pragma unroll
    for (int m2 = 0; m2 < 2; ++m2) {
        int r = (tid >> 4) + (m2 << 4);
        int c = (tid & 15) << 2;
        int t = ((r >> 2) << 9) + tbase + (r & 3);
        float4 a = *(const float4*)(x + (size_t)(b * TT + t) * EE + c);
        xs[r][c+0] = a.x; xs[r][c+1] = a.y; xs[r][c+2] = a.z; xs[r][c+3] = a.w;
    }
    __syncthreads();

    const int r = tid >> 3;
    const int d = tid & 7;
    float accq = bq[d], acck = bk[d], accv = bv[d];
#pragma unroll
    for (int e = 0; e < EE; ++e) {
        float xv = xs[r][e];
        accq = fmaf(xv, Wq[e*DD + d], accq);
        acck = fmaf(xv, Wk[e*DD + d], acck);
        accv = fmaf(xv, Wv[e*DD + d], accv);
    }
    qsm[tid] = (_Float16)(accq * QSCALE);
    ksm[((r & 3) << 6) + (d << 3) + (r >> 2)] = (_Float16)acck;
    vsm[(d << 5) + r] = (_Float16)accv;
    __syncthreads();

    // block-constant vP coordinates (t = g2x*512 + tbase + jx):
    //   i = g2x*8 + (tbase>>6), pv = (tbase>>5)&1, g2 = (tbase>>2)&3,
    //   j = jx + ((tbase&16)?4:0)   -> 4 contiguous halfs per (g2x,d)
    const int ilow = tbase >> 6;
    const int pv_  = (tbase >> 5) & 1;
    const int g2_  = (tbase >> 2) & 3;
    const int joff = (tbase & 16) ? 4 : 0;

    if (tid < 32) {
        half8 qv = *(half8*)(qsm + tid * 8);
        *(half8*)(qh + (size_t)b*(TT*DD) + (size_t)(tid >> 2)*(512*DD)
                     + (size_t)tbase*DD + ((tid & 3) << 3)) = qv;
        half8 kv = *(half8*)(ksm + tid * 8);
        *(half8*)(ks + (size_t)b*(TT*DD) + (size_t)tbase*64 + tid * 8) = kv;
    } else if (tid >= 64 && tid < 128) {
        int idx = tid - 64, d2 = idx >> 3, g2x = idx & 7;
        half4v vv = *(half4v*)(vsm + (d2 << 5) + (g2x << 2));
        const int i_ = (g2x << 3) + ilow;
        *(half4v*)(vP + (size_t)b*VP_BATCH + (size_t)i_*1024 + pv_*512
                      + (g2_ << 7) + (d2 << 3) + joff) = vv;
    } else if (tid >= 128 && tid < 136) {
        int g2x = tid & 7;
        const int i_ = (g2x << 3) + ilow;
        half4v ones = {(_Float16)1.0f, (_Float16)1.0f, (_Float16)1.0f, (_Float16)1.0f};
        *(half4v*)(vP + (size_t)b*VP_BATCH + (size_t)i_*1024 + pv_*512
                      + (g2_ << 7) + (8 << 3) + joff) = ones;
    }
}

// ---------------------------------------------------------------------------
// Kernel 2: MFMA flash attention, fixed-shift softmax. Round-8:
//  - V loads are 2 x b128 CONTIGUOUS 1-KB wave transactions (vP pre-swizzle)
//    replacing the 8KB-strided loads that line-split at the TA/L1 since r2.
//  - XCD batch swizzle: bb = blk&7 -> each XCD works one batch, K/V fully
//    L2-resident per XCD (250 KB).
// ---------------------------------------------------------------------------
__global__ __launch_bounds__(512, 4) void attn_kernel(
    const _Float16* __restrict__ qh, const _Float16* __restrict__ ks,
    const _Float16* __restrict__ vP, float* __restrict__ out)
{
    __shared__ floatx4 obuf[2][8][64];

    const int lane = threadIdx.x & 63;
    const int wave = threadIdx.x >> 6;
    const int g = lane >> 4;
    const int n = lane & 15;

    const int blk = blockIdx.x;
    const int bb  = blk & 7;          // XCD swizzle: one batch per XCD
    const int p   = blk >> 3;
    const int ntA = (p >> 2) + 1;
    const int ntB = ((255 - p) >> 2) + 1;
    const int r0A = p << 4;
    const int r0B = (255 - p) << 4;

    const _Float16* ksb = ks + (size_t)bb * (TT*DD);
    const _Float16* vPb = vP + (size_t)bb * VP_BATCH + (lane << 3);

    half8 qfA, qfB;
    {
        half8 z;
#pragma unroll
        for (int j = 0; j < 8; ++j) z[j] = (_Float16)0.0f;
        qfA = z; qfB = z;
        if (g == 0) {
            qfA = *(const half8*)(qh + ((size_t)bb*TT + r0A + n) * DD);
            qfB = *(const half8*)(qh + ((size_t)bb*TT + r0B + n) * DD);
        }
    }

    floatx4 oA = {0.f, 0.f, 0.f, 0.f};
    floatx4 oB = {0.f, 0.f, 0.f, 0.f};
    const floatx4 C12 = {CSHIFT, CSHIFT, CSHIFT, CSHIFT};

#define ATTN_LOOP(NT, R0, QF, OACC)                                             \
    for (int i = wave; i < (NT); i += 8) {                                      \
        const int t2base = i << 6;                                              \
        const _Float16* kp = ksb + (size_t)(t2base + n) * DD;                   \
        half8 ck0 = *(const half8*)(kp);                                        \
        half8 ck1 = *(const half8*)(kp + 16 * DD);                              \
        half8 ck2 = *(const half8*)(kp + 32 * DD);                              \
        half8 ck3 = *(const half8*)(kp + 48 * DD);                              \
        half8 va0 = *(const half8*)(vPb + (size_t)i * 1024);                    \
        half8 va1 = *(const half8*)(vPb + (size_t)i * 1024 + 512);              \
        floatx4 S[4];                                                           \
        S[0] = __builtin_amdgcn_mfma_f32_16x16x32_f16(ck0, QF, C12, 0, 0, 0);   \
        S[1] = __builtin_amdgcn_mfma_f32_16x16x32_f16(ck1, QF, C12, 0, 0, 0);   \
        S[2] = __builtin_amdgcn_mfma_f32_16x16x32_f16(ck2, QF, C12, 0, 0, 0);   \
        S[3] = __builtin_amdgcn_mfma_f32_16x16x32_f16(ck3, QF, C12, 0, 0, 0);   \
        if (t2base + 63 > (R0)) {                                               \
            const int lim = (R0) + n - t2base - (g << 2);                       \
            _Pragma("unroll")                                                   \
            for (int s = 0; s < 4; ++s)                                         \
                _Pragma("unroll")                                               \
                for (int rr = 0; rr < 4; ++rr)                                  \
                    if ((s << 4) + rr > lim) S[s][rr] = -INFINITY;              \
        }                                                                       \
        int lo[4], hi[4];                                                       \
        _Pragma("unroll")                                                       \
        for (int s = 0; s < 4; ++s) {                                           \
            float p0 = __builtin_amdgcn_exp2f(S[s][0]);                         \
            float p1 = __builtin_amdgcn_exp2f(S[s][1]);                         \
            float p2 = __builtin_amdgcn_exp2f(S[s][2]);                         \
            float p3 = __builtin_amdgcn_exp2f(S[s][3]);                         \
            lo[s] = __builtin_bit_cast(int, __builtin_amdgcn_cvt_pkrtz(p0, p1));\
            hi[s] = __builtin_bit_cast(int, __builtin_amdgcn_cvt_pkrtz(p2, p3));\
        }                                                                       \
        /* PV0: subtiles 0,1 (t2 0..31) — own-register B, contiguous V */       \
        {                                                                       \
            int4 bi; bi.x = lo[0]; bi.y = hi[0]; bi.z = lo[1]; bi.w = hi[1];    \
            half8 pb = __builtin_bit_cast(half8, bi);                           \
            OACC = __builtin_amdgcn_mfma_f32_16x16x32_f16(va0, pb, OACC, 0, 0, 0);\
        }                                                                       \
        /* PV1: subtiles 2,3 (t2 32..63) */                                     \
        {                                                                       \
            int4 bi; bi.x = lo[2]; bi.y = hi[2]; bi.z = lo[3]; bi.w = hi[3];    \
            half8 pb = __builtin_bit_cast(half8, bi);                           \
            OACC = __builtin_amdgcn_mfma_f32_16x16x32_f16(va1, pb, OACC, 0, 0, 0);\
        }                                                                       \
    }

    ATTN_LOOP(ntA, r0A, qfA, oA)
    ATTN_LOOP(ntB, r0B, qfB, oB)
#undef ATTN_LOOP

    obuf[0][wave][lane] = oA;
    obuf[1][wave][lane] = oB;
    __syncthreads();

    // ---- merge: plain sum of 8 partials (fixed shift -> no rebasing) ----
    if (wave < 2) {
        floatx4 osum = {0.f, 0.f, 0.f, 0.f};
#pragma unroll
        for (int w = 0; w < 8; ++w) osum += obuf[wave][w][lane];
        const float l    = __shfl(osum[0], 32 + n, 64);  // O^T[8][t1]
        const float linv = 1.0f / l;
        const int   r0   = wave ? r0B : r0A;
        if (g < 2) {
            float4 res;
            res.x = osum[0] * linv; res.y = osum[1] * linv;
            res.z = osum[2] * linv; res.w = osum[3] * linv;
            *(float4*)(out + (((size_t)bb * TT + r0 + n) * DD) + (g << 2)) = res;
        }
    }
}

extern "C" void kernel_launch(void* const* d_in, const int* in_sizes, int n_in,
                              void* d_out, int out_size, void* d_ws, size_t ws_size,
                              hipStream_t stream) {
    const float* x  = (const float*)d_in[0];
    const float* Wq = (const float*)d_in[1];
    const float* bq = (const float*)d_in[2];
    const float* Wk = (const float*)d_in[3];
    const float* bk = (const float*)d_in[4];
    const float* Wv = (const float*)d_in[5];
    const float* bv = (const float*)d_in[6];
    float* out = (float*)d_out;

    _Float16* qhp = (_Float16*)d_ws;                       // B*T*D
    _Float16* ksp = qhp + (size_t)BB * TT * DD;            // B*T*D
    _Float16* vPp = ksp + (size_t)BB * TT * DD;            // B*VP_BATCH

    proj_kernel<<<BB * TT / 32, 256, 0, stream>>>(x, Wq, bq, Wk, bk, Wv, bv, qhp, ksp, vPp);
    attn_kernel<<<1024, 512, 0, stream>>>(qhp, ksp, vPp, out);
}

// Round 9
// 86.848 us; speedup vs baseline: 1.3291x; 1.0421x over previous
//
#include <hip/hip_runtime.h>
#include <math.h>

#define BB 8
#define TT 4096
#define EE 64
#define DD 8
// (1/sqrt(8)) * log2(e): folded into q so p = exp2(score) directly
#define QSCALE 0.51012604f
// fixed softmax shift, implemented as MFMA C-init; cancels in normalization
#define CSHIFT -12.0f

typedef _Float16 half8  __attribute__((ext_vector_type(8)));
typedef _Float16 half4v __attribute__((ext_vector_type(4)));
typedef float    floatx4 __attribute__((ext_vector_type(4)));

// vP: per batch, 64 items x [pv:2] x [lane:64] x 8 halfs = 65536 halfs.
// vP[i][pv][g*16+n][j] = V^T[n][i*64 + pv*32 + (j<4 ? g*4+j : 16+g*4+j-4)]
// (n=8 -> 1.0 denominator row; n>8 garbage/ignored)
#define VP_BATCH 65536

// ---------------------------------------------------------------------------
// Kernel 1: projections (unchanged from round 8). ks "reshape" scatter = one
// contiguous 512-B region; V pre-swizzled into PV A-operand lane order.
// ---------------------------------------------------------------------------
__global__ __launch_bounds__(256) void proj_kernel(
    const float* __restrict__ x,
    const float* __restrict__ Wq, const float* __restrict__ bq,
    const float* __restrict__ Wk, const float* __restrict__ bk,
    const float* __restrict__ Wv, const float* __restrict__ bv,
    _Float16* __restrict__ qh, _Float16* __restrict__ ks, _Float16* __restrict__ vP)
{
    __shared__ float    xs[32][EE + 1];
    __shared__ _Float16 qsm[256];   // [g2x][jx][d] == tid order
    __shared__ _Float16 ksm[256];   // [jx][d][g2x]
    __shared__ _Float16 vsm[256];   // [d][r]  (r = g2x*4 + jx)

    const int tid   = threadIdx.x;
    const int blk   = blockIdx.x;
    const int b     = blk >> 7;
    const int tbase = (blk & 127) << 2;

#pragma unroll
    for (int m2 = 0; m2 < 2; ++m2) {
        int r = (tid >> 4) + (m2 << 4);
        int c = (tid & 15) << 2;
        int t = ((r >> 2) << 9) + tbase + (r & 3);
        float4 a = *(const float4*)(x + (size_t)(b * TT + t) * EE + c);
        xs[r][c+0] = a.x; xs[r][c+1] = a.y; xs[r][c+2] = a.z; xs[r][c+3] = a.w;
    }
    __syncthreads();

    const int r = tid >> 3;
    const int d = tid & 7;
    float accq = bq[d], acck = bk[d], accv = bv[d];
#pragma unroll
    for (int e = 0; e < EE; ++e) {
        float xv = xs[r][e];
        accq = fmaf(xv, Wq[e*DD + d], accq);
        acck = fmaf(xv, Wk[e*DD + d], acck);
        accv = fmaf(xv, Wv[e*DD + d], accv);
    }
    qsm[tid] = (_Float16)(accq * QSCALE);
    ksm[((r & 3) << 6) + (d << 3) + (r >> 2)] = (_Float16)acck;
    vsm[(d << 5) + r] = (_Float16)accv;
    __syncthreads();

    const int ilow = tbase >> 6;
    const int pv_  = (tbase >> 5) & 1;
    const int g2_  = (tbase >> 2) & 3;
    const int joff = (tbase & 16) ? 4 : 0;

    if (tid < 32) {
        half8 qv = *(half8*)(qsm + tid * 8);
        *(half8*)(qh + (size_t)b*(TT*DD) + (size_t)(tid >> 2)*(512*DD)
                     + (size_t)tbase*DD + ((tid & 3) << 3)) = qv;
        half8 kv = *(half8*)(ksm + tid * 8);
        *(half8*)(ks + (size_t)b*(TT*DD) + (size_t)tbase*64 + tid * 8) = kv;
    } else if (tid >= 64 && tid < 128) {
        int idx = tid - 64, d2 = idx >> 3, g2x = idx & 7;
        half4v vv = *(half4v*)(vsm + (d2 << 5) + (g2x << 2));
        const int i_ = (g2x << 3) + ilow;
        *(half4v*)(vP + (size_t)b*VP_BATCH + (size_t)i_*1024 + pv_*512
                      + (g2_ << 7) + (d2 << 3) + joff) = vv;
    } else if (tid >= 128 && tid < 136) {
        int g2x = tid & 7;
        const int i_ = (g2x << 3) + ilow;
        half4v ones = {(_Float16)1.0f, (_Float16)1.0f, (_Float16)1.0f, (_Float16)1.0f};
        *(half4v*)(vP + (size_t)b*VP_BATCH + (size_t)i_*1024 + pv_*512
                      + (g2_ << 7) + (8 << 3) + joff) = ones;
    }
}

// ---------------------------------------------------------------------------
// Kernel 2: MFMA flash attention, fixed-shift softmax. Round-9:
//  QUAD-TILE BLOCKS: each block owns row-tiles (2p, 2p+1, 254-2p, 255-2p).
//  Adjacent tiles share identical item extents ((2p)>>2 == (2p+1)>>2), so
//  one K/V load now feeds 32 rows instead of 16 -> L2 traffic halves
//  (400 -> 200 MB). Balance preserved: ntA + ntB = 65 items per block
//  exactly (floor(a/4)+floor(b/4) = 63 for a+b = 256, both odd).
//  512 blocks x 512 thr; VGPR live-set ~96 -> launch_bounds(512,4) = cap 128.
// ---------------------------------------------------------------------------
__global__ __launch_bounds__(512, 4) void attn_kernel(
    const _Float16* __restrict__ qh, const _Float16* __restrict__ ks,
    const _Float16* __restrict__ vP, float* __restrict__ out)
{
    __shared__ floatx4 obuf[4][8][64];

    const int lane = threadIdx.x & 63;
    const int wave = threadIdx.x >> 6;
    const int g = lane >> 4;
    const int n = lane & 15;

    const int blk = blockIdx.x;
    const int bb  = blk & 7;          // XCD swizzle: one batch per XCD
    const int p   = blk >> 3;         // 0..63
    const int r0A = p << 5;           // tiles 2p (rows r0A..) and 2p+1
    const int r0B = (127 - p) << 5;   // tiles 254-2p and 255-2p
    const int ntA = (p >> 1) + 1;             // = ((2p+1)>>2)+1 too
    const int ntB = ((255 - (p << 1)) >> 2) + 1;

    const _Float16* ksb = ks + (size_t)bb * (TT*DD);
    const _Float16* vPb = vP + (size_t)bb * VP_BATCH + (lane << 3);

    half8 qfA0, qfA1, qfB0, qfB1;
    {
        half8 z;
#pragma unroll
        for (int j = 0; j < 8; ++j) z[j] = (_Float16)0.0f;
        qfA0 = z; qfA1 = z; qfB0 = z; qfB1 = z;
        if (g == 0) {
            qfA0 = *(const half8*)(qh + ((size_t)bb*TT + r0A + n) * DD);
            qfA1 = *(const half8*)(qh + ((size_t)bb*TT + r0A + 16 + n) * DD);
            qfB0 = *(const half8*)(qh + ((size_t)bb*TT + r0B + n) * DD);
            qfB1 = *(const half8*)(qh + ((size_t)bb*TT + r0B + 16 + n) * DD);
        }
    }

    floatx4 oA0 = {0.f,0.f,0.f,0.f}, oA1 = {0.f,0.f,0.f,0.f};
    floatx4 oB0 = {0.f,0.f,0.f,0.f}, oB1 = {0.f,0.f,0.f,0.f};
    const floatx4 C12 = {CSHIFT, CSHIFT, CSHIFT, CSHIFT};

// one row-tile's St -> mask -> exp -> PV, using the item's shared K/V regs
#define TILE_BODY(QF, R0, OACC)                                                 \
    {                                                                           \
        floatx4 S[4];                                                           \
        S[0] = __builtin_amdgcn_mfma_f32_16x16x32_f16(ck0, QF, C12, 0, 0, 0);   \
        S[1] = __builtin_amdgcn_mfma_f32_16x16x32_f16(ck1, QF, C12, 0, 0, 0);   \
        S[2] = __builtin_amdgcn_mfma_f32_16x16x32_f16(ck2, QF, C12, 0, 0, 0);   \
        S[3] = __builtin_amdgcn_mfma_f32_16x16x32_f16(ck3, QF, C12, 0, 0, 0);   \
        if (t2base + 63 > (R0)) {                                               \
            const int lim = (R0) + n - t2base - (g << 2);                       \
            _Pragma("unroll")                                                   \
            for (int s = 0; s < 4; ++s)                                         \
                _Pragma("unroll")                                               \
                for (int rr = 0; rr < 4; ++rr)                                  \
                    if ((s << 4) + rr > lim) S[s][rr] = -INFINITY;              \
        }                                                                       \
        int lo[4], hi[4];                                                       \
        _Pragma("unroll")                                                       \
        for (int s = 0; s < 4; ++s) {                                           \
            float p0 = __builtin_amdgcn_exp2f(S[s][0]);                         \
            float p1 = __builtin_amdgcn_exp2f(S[s][1]);                         \
            float p2 = __builtin_amdgcn_exp2f(S[s][2]);                         \
            float p3 = __builtin_amdgcn_exp2f(S[s][3]);                         \
            lo[s] = __builtin_bit_cast(int, __builtin_amdgcn_cvt_pkrtz(p0, p1));\
            hi[s] = __builtin_bit_cast(int, __builtin_amdgcn_cvt_pkrtz(p2, p3));\
        }                                                                       \
        {                                                                       \
            int4 bi; bi.x = lo[0]; bi.y = hi[0]; bi.z = lo[1]; bi.w = hi[1];    \
            half8 pb = __builtin_bit_cast(half8, bi);                           \
            OACC = __builtin_amdgcn_mfma_f32_16x16x32_f16(va0, pb, OACC, 0, 0, 0);\
        }                                                                       \
        {                                                                       \
            int4 bi; bi.x = lo[2]; bi.y = hi[2]; bi.z = lo[3]; bi.w = hi[3];    \
            half8 pb = __builtin_bit_cast(half8, bi);                           \
            OACC = __builtin_amdgcn_mfma_f32_16x16x32_f16(va1, pb, OACC, 0, 0, 0);\
        }                                                                       \
    }

#define ATTN_LOOP2(NT, R0LO, QF0, QF1, O0, O1)                                  \
    for (int i = wave; i < (NT); i += 8) {                                      \
        const int t2base = i << 6;                                              \
        const _Float16* kp = ksb + (size_t)(t2base + n) * DD;                   \
        half8 ck0 = *(const half8*)(kp);                                        \
        half8 ck1 = *(const half8*)(kp + 16 * DD);                              \
        half8 ck2 = *(const half8*)(kp + 32 * DD);                              \
        half8 ck3 = *(const half8*)(kp + 48 * DD);                              \
        half8 va0 = *(const half8*)(vPb + (size_t)i * 1024);                    \
        half8 va1 = *(const half8*)(vPb + (size_t)i * 1024 + 512);              \
        TILE_BODY(QF0, (R0LO), O0)                                              \
        TILE_BODY(QF1, (R0LO) + 16, O1)                                         \
    }

    ATTN_LOOP2(ntA, r0A, qfA0, qfA1, oA0, oA1)
    ATTN_LOOP2(ntB, r0B, qfB0, qfB1, oB0, oB1)
#undef ATTN_LOOP2
#undef TILE_BODY

    obuf[0][wave][lane] = oA0;
    obuf[1][wave][lane] = oA1;
    obuf[2][wave][lane] = oB0;
    obuf[3][wave][lane] = oB1;
    __syncthreads();

    // ---- merge: plain sum of 8 partials per tile (fixed shift) ----
    if (wave < 4) {
        floatx4 osum = {0.f, 0.f, 0.f, 0.f};
#pragma unroll
        for (int w = 0; w < 8; ++w) osum += obuf[wave][w][lane];
        const float l    = __shfl(osum[0], 32 + n, 64);  // O^T[8][t1]
        const float linv = 1.0f / l;
        const int   r0   = ((wave & 2) ? r0B : r0A) + ((wave & 1) << 4);
        if (g < 2) {
            float4 res;
            res.x = osum[0] * linv; res.y = osum[1] * linv;
            res.z = osum[2] * linv; res.w = osum[3] * linv;
            *(float4*)(out + (((size_t)bb * TT + r0 + n) * DD) + (g << 2)) = res;
        }
    }
}

extern "C" void kernel_launch(void* const* d_in, const int* in_sizes, int n_in,
                              void* d_out, int out_size, void* d_ws, size_t ws_size,
                              hipStream_t stream) {
    const float* x  = (const float*)d_in[0];
    const float* Wq = (const float*)d_in[1];
    const float* bq = (const float*)d_in[2];
    const float* Wk = (const float*)d_in[3];
    const float* bk = (const float*)d_in[4];
    const float* Wv = (const float*)d_in[5];
    const float* bv = (const float*)d_in[6];
    float* out = (float*)d_out;

    _Float16* qhp = (_Float16*)d_ws;                       // B*T*D
    _Float16* ksp = qhp + (size_t)BB * TT * DD;            // B*T*D
    _Float16* vPp = ksp + (size_t)BB * TT * DD;            // B*VP_BATCH

    proj_kernel<<<BB * TT / 32, 256, 0, stream>>>(x, Wq, bq, Wk, bk, Wv, bv, qhp, ksp, vPp);
    attn_kernel<<<512, 512, 0, stream>>>(qhp, ksp, vPp, out);
}